// Round 2
// 453.615 us; speedup vs baseline: 1.0025x; 1.0025x over previous
//
#include <hip/hip_runtime.h>
#include <cstdint>

#define NH 16
#define HD 128
#define BS 16
#define NTBL 96
#define PT_OFF 32            // prompt blocks skipped: 512/16
#define NSPLIT 16
#define SPLIT_BLOCKS 4       // 64 positions per split
#define QK_SCALE 0.08838834764831845f
#define NEG_INF -1e30f
#define NB 16                // batch

// Flash-decoding split over the CACHED positions [0, ctx-1) only.
// The new token (position ctx-1, k_new/v_new) is merged in reduce_kernel,
// so the paged caches are never written.
//
// R1/R2: ALL global loads (q, bias, K-block, V-block->regs) are issued
// up front, before the first barrier. Previously the WG serialized three
// dependence-free memory phases (K ... sync ... bias ... sync ... V), paying
// three HBM round-trips; now the single vmcnt(0) drain at the first barrier
// covers everything in flight concurrently. R2 adds zero-init of the
// conditional V registers (hygiene; no semantic change).
__global__ __launch_bounds__(256, 4) void attn_split_kernel(
    const float* __restrict__ q,
    const float* __restrict__ key_cache,
    const float* __restrict__ value_cache,
    const int* __restrict__ block_tables,
    const int* __restrict__ context_lens,
    const float* __restrict__ attn_bias,
    float* __restrict__ ws)
{
    const int s = blockIdx.x, h = blockIdx.y, b = blockIdx.z;
    const int ctx = context_lens[b];
    const int cap = ctx - 1;                 // cached positions: [0, cap)
    const int nbc = (ctx + 14) >> 4;         // ceil(cap/16) blocks
    const int jb0 = s * SPLIT_BLOCKS;
    if (jb0 >= nbc) return;                  // inactive split (uniform per WG)
    const int nbl = min(SPLIT_BLOCKS, nbc - jb0);

    __shared__ float sc[64];                 // raw dots
    __shared__ float sp[64];                 // probs
    __shared__ float outA[128], outB[128];

    const int tid = threadIdx.x;
    const int wave = tid >> 6, lane = tid & 63;
    const int half = lane >> 5, lq = lane & 31;
    const int team = tid >> 7, d = tid & 127;

    const int tbl = b*NTBL + PT_OFF + jb0;

    // ---------------- issue phase: every global load goes out NOW ----------
    // query fragment: dims [lq*4, lq*4+4)
    const float4 qv = *(const float4*)(q + (size_t)b*2048 + h*HD + lq*4);

    // bias for this lane's softmax position (used after first barrier)
    const int gpos = jb0*16 + lane;
    const bool valid = gpos < cap;           // also masks lane >= nbl*16
    const float biasv = valid
        ? attn_bias[((size_t)b*NH + h)*1024 + gpos] : 0.0f;

    // V blocks for this thread's team (jl = team, team+2) -> registers.
    // Named float4s => static register indices, no scratch.
    const bool vact0 = (team)     < nbl;
    const bool vact1 = (team + 2) < nbl;
    float4 v00 = {0,0,0,0}, v01 = {0,0,0,0}, v02 = {0,0,0,0}, v03 = {0,0,0,0};
    float4 v10 = {0,0,0,0}, v11 = {0,0,0,0}, v12 = {0,0,0,0}, v13 = {0,0,0,0};
    if (vact0) {
        const int blk = block_tables[tbl + team];
        const float4* vb = (const float4*)(value_cache + ((size_t)blk*NH + h)*2048 + d*16);
        v00 = vb[0]; v01 = vb[1]; v02 = vb[2]; v03 = vb[3];
    }
    if (vact1) {
        const int blk = block_tables[tbl + team + 2];
        const float4* vb = (const float4*)(value_cache + ((size_t)blk*NH + h)*2048 + d*16);
        v10 = vb[0]; v11 = vb[1]; v12 = vb[2]; v13 = vb[3];
    }

    // K block for this wave: coalesced float4 stream + shfl dot-reduce.
    const bool kact = wave < nbl;
    if (kact) {
        const int kblk = block_tables[tbl + wave];
        const float4* kb = (const float4*)(key_cache + ((size_t)kblk*NH + h)*2048);
        #pragma unroll
        for (int i = 0; i < 8; ++i) {
            const float4 kv = kb[i*64 + lane];
            float part = kv.x*qv.x + kv.y*qv.y + kv.z*qv.z + kv.w*qv.w;
            part += __shfl_xor(part, 1);
            part += __shfl_xor(part, 2);
            part += __shfl_xor(part, 4);
            part += __shfl_xor(part, 8);
            part += __shfl_xor(part, 16);   // 32-lane half holds full 128-dim dot
            if (lq == 0) sc[wave*16 + i*2 + half] = part;
        }
    }
    __syncthreads();   // single vmcnt(0) drain covers K + V + bias + q together

    // ---- softmax over <=64 positions, computed redundantly per wave (lane==pos)
    const float x = valid ? (sc[lane]*QK_SCALE + biasv) : NEG_INF;
    float m = x;
    #pragma unroll
    for (int msk = 32; msk >= 1; msk >>= 1) m = fmaxf(m, __shfl_xor(m, msk));
    const float pexp = valid ? __expf(x - m) : 0.0f;
    float l = pexp;
    #pragma unroll
    for (int msk = 32; msk >= 1; msk >>= 1) l += __shfl_xor(l, msk);
    if (wave == 0) sp[lane] = pexp;
    __syncthreads();

    // ---- PV: thread owns dim d; V already in registers, probs via LDS broadcast
    float acc = 0.0f;
    if (vact0) {
        const float* pr = sp + team*16;
        acc += pr[0]*v00.x  + pr[1]*v00.y  + pr[2]*v00.z  + pr[3]*v00.w;
        acc += pr[4]*v01.x  + pr[5]*v01.y  + pr[6]*v01.z  + pr[7]*v01.w;
        acc += pr[8]*v02.x  + pr[9]*v02.y  + pr[10]*v02.z + pr[11]*v02.w;
        acc += pr[12]*v03.x + pr[13]*v03.y + pr[14]*v03.z + pr[15]*v03.w;
    }
    if (vact1) {
        const float* pr = sp + (team+2)*16;
        acc += pr[0]*v10.x  + pr[1]*v10.y  + pr[2]*v10.z  + pr[3]*v10.w;
        acc += pr[4]*v11.x  + pr[5]*v11.y  + pr[6]*v11.z  + pr[7]*v11.w;
        acc += pr[8]*v12.x  + pr[9]*v12.y  + pr[10]*v12.z + pr[11]*v12.w;
        acc += pr[12]*v13.x + pr[13]*v13.y + pr[14]*v13.z + pr[15]*v13.w;
    }
    if (team == 0) outA[d] = acc; else outB[d] = acc;
    __syncthreads();

    float* wsp = ws + (((size_t)b*NH + h)*NSPLIT + s)*130;
    if (tid < 128) wsp[tid] = outA[tid] + outB[tid];
    if (tid == 0) { wsp[128] = m; wsp[129] = l; }
}

// Merge split partials + the new token (k_new/v_new at position ctx-1).
__global__ __launch_bounds__(128) void reduce_kernel(
    const float* __restrict__ ws,
    const float* __restrict__ q,
    const float* __restrict__ k_new,
    const float* __restrict__ v_new,
    const int* __restrict__ context_lens,
    const float* __restrict__ attn_bias,
    float* __restrict__ out)
{
    const int h = blockIdx.x, b = blockIdx.y, d = threadIdx.x;
    const int wave = d >> 6, lane = d & 63;
    const int ctx = context_lens[b];
    const int cap = ctx - 1;
    const int nbc = (ctx + 14) >> 4;
    const int nsv = (nbc + SPLIT_BLOCKS - 1) >> 2;   // active splits (may be 0)

    const size_t qoff = (size_t)b*2048 + h*HD + d;
    const float qd = q[qoff], kd = k_new[qoff], vd = v_new[qoff];

    float p = qd * kd;
    #pragma unroll
    for (int msk = 32; msk >= 1; msk >>= 1) p += __shfl_xor(p, msk);
    __shared__ float s2[2];
    if (lane == 0) s2[wave] = p;
    __syncthreads();
    const float score_new = (s2[0] + s2[1]) * QK_SCALE
                          + attn_bias[((size_t)b*NH + h)*1024 + cap];

    const float* base = ws + ((size_t)b*NH + h)*NSPLIT*130;
    float M = score_new;
    for (int s = 0; s < nsv; ++s) M = fmaxf(M, base[s*130 + 128]);
    const float w = __expf(score_new - M);
    float L = w, acc = w * vd;
    for (int s = 0; s < nsv; ++s) {
        const float e = __expf(base[s*130 + 128] - M);
        L   += base[s*130 + 129] * e;
        acc += base[s*130 + d] * e;
    }
    out[qoff] = acc / L;
}

extern "C" void kernel_launch(void* const* d_in, const int* in_sizes, int n_in,
                              void* d_out, int out_size, void* d_ws, size_t ws_size,
                              hipStream_t stream) {
    (void)in_sizes; (void)n_in; (void)out_size; (void)ws_size;
    const float* q        = (const float*)d_in[0];
    const float* k_new    = (const float*)d_in[1];
    const float* v_new    = (const float*)d_in[2];
    const float* kcache   = (const float*)d_in[3];
    const float* vcache   = (const float*)d_in[4];
    const int* btables    = (const int*)d_in[6];
    const int* ctx_lens   = (const int*)d_in[7];
    const float* bias     = (const float*)d_in[8];
    float* ws  = (float*)d_ws;   // needs 16*16*16*130*4 = 532480 B
    float* out = (float*)d_out;

    attn_split_kernel<<<dim3(NSPLIT, NH, NB), 256, 0, stream>>>(
        q, kcache, vcache, btables, ctx_lens, bias, ws);
    reduce_kernel<<<dim3(NH, NB), 128, 0, stream>>>(
        ws, q, k_new, v_new, ctx_lens, bias, out);
}